// Round 2
// baseline (1828.031 us; speedup 1.0000x reference)
//
#include <hip/hip_runtime.h>
#include <hip/hip_bf16.h>

// Problem constants
#define TT 16
#define MM 1024
#define HDIM 128
#define NHEADS 4
#define NROWS (TT*MM)          // 16384
#define MAXDEG 64

// ---------------- mask + neighbor-list build ----------------
__global__ __launch_bounds__(256) void k_init(const int* __restrict__ ego,
                                              float* __restrict__ mfl,
                                              int* __restrict__ cnt) {
    int idx = blockIdx.x * 256 + threadIdx.x;   // < 16384
    int t = idx >> 10, i = idx & 1023;
    int b = i >> 8, n = i & 255;
    // ego_mask [B,T,N]: ego[b*T*N + t*N + n]
    mfl[idx] = ego[b * (TT * 256) + t * 256 + n] ? 1.f : 0.f;
    cnt[idx] = 0;
}

__global__ __launch_bounds__(256) void k_edges(const float* __restrict__ adj,
                                               const float* __restrict__ mfl,
                                               int* __restrict__ cnt,
                                               int* __restrict__ nbr) {
    int bid = blockIdx.x;            // 256 blocks: t(16) x jc(4) x ic(4)
    int t = bid >> 4, jc = (bid >> 2) & 3, ic = bid & 3;
    int tid = threadIdx.x;
    int i = ic * 256 + tid;
    int row = t * MM + i;
    __shared__ float ms[256];
    int j0 = jc * 256;
    ms[tid] = mfl[t * MM + j0 + tid];
    __syncthreads();
    float mi = mfl[row];
    if (mi == 0.f) return;           // no edges into masked-out i
    const float* at = adj + (size_t)t * MM * MM;
    for (int jj = 0; jj < 256; ++jj) {
        int j = j0 + jj;
        bool e;
        if (j == i) e = true;                                   // self-loop (mi!=0)
        else e = (at[(size_t)j * MM + i] != 0.f) && (ms[jj] != 0.f);
        if (e) {
            int pos = atomicAdd(&cnt[row], 1);
            if (pos < MAXDEG) nbr[(size_t)row * MAXDEG + pos] = j;
        }
    }
}

// ---------------- GAT layer 1 projection (F=2) ----------------
__global__ __launch_bounds__(256) void k_gat1_h(const float* __restrict__ x,
                                                const float* __restrict__ W,
                                                float* __restrict__ h) {
    int idx = blockIdx.x * 256 + threadIdx.x;   // < 16384*512
    int row = idx >> 9, o = idx & 511;
    h[idx] = x[row * 2] * W[o] + x[row * 2 + 1] * W[512 + o];
}

// ---------------- generic in-block GEMM: [16,K] (LDS) @ [K,OUT] (f32 global) ----------------
template <int K, int OUT, int OTILE>
__device__ __forceinline__ void gemm16(const float* __restrict__ Xs,
                                       const float* __restrict__ W,
                                       const float* bias,
                                       float* __restrict__ Out, bool relu) {
    constexpr int OG = OUT / OTILE;     // threads along o
    constexpr int RG = 256 / OG;        // row groups
    constexpr int RT = 16 / RG;         // rows per thread
    int tid = threadIdx.x;
    int og = tid & (OG - 1);
    int rg = tid / OG;
    int r0 = rg * RT;
    float acc[RT][OTILE];
#pragma unroll
    for (int r = 0; r < RT; ++r)
#pragma unroll
        for (int ot = 0; ot < OTILE; ++ot) acc[r][ot] = 0.f;
    for (int k = 0; k < K; k += 4) {
        float4 xv[RT];
#pragma unroll
        for (int r = 0; r < RT; ++r)
            xv[r] = *(const float4*)(Xs + (r0 + r) * K + k);
#pragma unroll
        for (int ot = 0; ot < OTILE; ++ot) {
            int o = og + ot * OG;
            float w0 = W[(k + 0) * OUT + o];
            float w1 = W[(k + 1) * OUT + o];
            float w2 = W[(k + 2) * OUT + o];
            float w3 = W[(k + 3) * OUT + o];
#pragma unroll
            for (int r = 0; r < RT; ++r)
                acc[r][ot] += xv[r].x * w0 + xv[r].y * w1 + xv[r].z * w2 + xv[r].w * w3;
        }
    }
#pragma unroll
    for (int ot = 0; ot < OTILE; ++ot) {
        int o = og + ot * OG;
        float bb = bias ? bias[o] : 0.f;
#pragma unroll
        for (int r = 0; r < RT; ++r) {
            float v = acc[r][ot] + bb;
            if (relu) v = fmaxf(v, 0.f);
            Out[(r0 + r) * OUT + o] = v;
        }
    }
}

// ---------------- GAT layers 2-6 projection (F=128) ----------------
__global__ __launch_bounds__(256) void k_gat_h(const float* __restrict__ x,
                                               const float* __restrict__ W,
                                               float* __restrict__ h) {
    __shared__ __align__(16) float Xs[16 * 128];
    int row0 = blockIdx.x * 16;
    int tid = threadIdx.x;
    for (int idx = tid; idx < 2048; idx += 256)
        Xs[idx] = x[(size_t)row0 * 128 + idx];
    __syncthreads();
    gemm16<128, 512, 4>(Xs, W, nullptr, h + (size_t)row0 * 512, false);
}

// ---------------- per-node attention scores (ss, sd) ----------------
__global__ __launch_bounds__(128) void k_ssd(const float* __restrict__ h,
                                             const float* __restrict__ asrc,
                                             const float* __restrict__ adst,
                                             float* __restrict__ ss, float* __restrict__ sd) {
    int row = blockIdx.x, tid = threadIdx.x;
    const float* hp = h + (size_t)row * 512;
    float s4[4], d4[4];
#pragma unroll
    for (int hh = 0; hh < 4; ++hh) {
        float v = hp[hh * 128 + tid];
        s4[hh] = v * asrc[hh * 128 + tid];
        d4[hh] = v * adst[hh * 128 + tid];
    }
#pragma unroll
    for (int hh = 0; hh < 4; ++hh)
        for (int off = 32; off; off >>= 1) {
            s4[hh] += __shfl_down(s4[hh], off, 64);
            d4[hh] += __shfl_down(d4[hh], off, 64);
        }
    __shared__ float red[2][2][4];
    if ((tid & 63) == 0) {
        int w = tid >> 6;
#pragma unroll
        for (int hh = 0; hh < 4; ++hh) { red[w][0][hh] = s4[hh]; red[w][1][hh] = d4[hh]; }
    }
    __syncthreads();
    if (tid < 4) ss[row * 4 + tid] = red[0][0][tid] + red[1][0][tid];
    else if (tid < 8) sd[row * 4 + tid - 4] = red[0][1][tid - 4] + red[1][1][tid - 4];
}

// ---------------- GAT aggregation (segment softmax + gather) ----------------
__global__ __launch_bounds__(128) void k_agg(const float* __restrict__ h,
                                             const float* __restrict__ ss,
                                             const float* __restrict__ sd,
                                             const int* __restrict__ cnt,
                                             const int* __restrict__ nbr,
                                             const float* __restrict__ mfl,
                                             const float* __restrict__ bias,
                                             float* __restrict__ xo) {
    int row = blockIdx.x, tid = threadIdx.x;
    int t = row >> 10;
    if (mfl[row] == 0.f) { xo[(size_t)row * 128 + tid] = 0.f; return; }
    int c = cnt[row]; if (c > MAXDEG) c = MAXDEG;
    __shared__ int nb[MAXDEG];
    __shared__ float al[MAXDEG][4];
    if (tid < c) nb[tid] = nbr[(size_t)row * MAXDEG + tid];
    __syncthreads();
    for (int idx = tid; idx < c * 4; idx += 128) {
        int n = idx >> 2, hh = idx & 3, j = nb[n];
        float lg = sd[row * 4 + hh] + ss[(t * MM + j) * 4 + hh];
        al[n][hh] = lg > 0.f ? lg : 0.2f * lg;   // leaky_relu 0.2
    }
    __syncthreads();
    if (tid < 4) {
        float mx = -1e30f;
        for (int n = 0; n < c; ++n) mx = fmaxf(mx, al[n][tid]);
        float s = 0.f;
        for (int n = 0; n < c; ++n) { float e = __expf(al[n][tid] - mx); al[n][tid] = e; s += e; }
        float inv = 1.f / s;
        for (int n = 0; n < c; ++n) al[n][tid] *= inv;
    }
    __syncthreads();
    float a0 = 0, a1 = 0, a2 = 0, a3 = 0;
    for (int n = 0; n < c; ++n) {
        int j = nb[n];
        const float* hp = h + ((size_t)(t * MM + j)) * 512 + tid;
        a0 += al[n][0] * hp[0];
        a1 += al[n][1] * hp[128];
        a2 += al[n][2] * hp[256];
        a3 += al[n][3] * hp[384];
    }
    float v = 0.25f * (a0 + a1 + a2 + a3) + bias[tid];
    xo[(size_t)row * 128 + tid] = fmaxf(v, 0.f);
}

// ---------------- residual add + LayerNorm (in-block, 16 rows x 128) ----------------
__device__ __forceinline__ void addln(float* xs, const float* tb,
                                      const float* s, const float* b) {
    int tid = threadIdx.x;
    for (int idx = tid; idx < 2048; idx += 256) xs[idx] += tb[idx];
    __syncthreads();
    int row = tid >> 4, lane = tid & 15;
    float sum = 0.f;
#pragma unroll
    for (int k2 = 0; k2 < 8; ++k2) sum += xs[row * 128 + lane + 16 * k2];
#pragma unroll
    for (int off = 8; off; off >>= 1) sum += __shfl_xor(sum, off, 16);
    float mean = sum * (1.f / 128.f);
    float vs = 0.f;
#pragma unroll
    for (int k2 = 0; k2 < 8; ++k2) { float d = xs[row * 128 + lane + 16 * k2] - mean; vs += d * d; }
#pragma unroll
    for (int off = 8; off; off >>= 1) vs += __shfl_xor(vs, off, 16);
    float rstd = rsqrtf(vs * (1.f / 128.f) + 1e-5f);
#pragma unroll
    for (int k2 = 0; k2 < 8; ++k2) {
        int d = lane + 16 * k2;
        float v = (xs[row * 128 + d] - mean) * rstd;
        xs[row * 128 + d] = v * s[d] + b[d];
    }
    __syncthreads();
}

// ---------------- full 5-layer transformer, one block per sequence ----------------
__global__ __launch_bounds__(256) void k_tf(const float* __restrict__ xg,
        const float* __restrict__ Wqkv, const float* __restrict__ bqkv,
        const float* __restrict__ Wo,   const float* __restrict__ bo,
        const float* __restrict__ ln1s, const float* __restrict__ ln1b,
        const float* __restrict__ ln2s, const float* __restrict__ ln2b,
        const float* __restrict__ Wff1, const float* __restrict__ bff1,
        const float* __restrict__ Wff2, const float* __restrict__ bff2,
        float* __restrict__ out) {
    int m = blockIdx.x, tid = threadIdx.x;
    __shared__ __align__(16) float xs[2048];
    __shared__ __align__(16) float qb[2048];
    __shared__ __align__(16) float kb[2048];
    __shared__ __align__(16) float vb[2048];
    __shared__ __align__(16) float tb[2048];
    __shared__ __align__(16) float hid[8192];
    __shared__ __align__(16) float sc[1024];

    // load + sinusoidal PE
    for (int idx = tid; idx < 2048; idx += 256) {
        int t = idx >> 7, d = idx & 127, jj = d >> 1;
        float arg = (float)t * expf(-(float)(2 * jj) * (9.210340371976184f / 128.f));
        float pe = (d & 1) ? cosf(arg) : sinf(arg);
        xs[idx] = xg[(size_t)t * (MM * HDIM) + (size_t)m * HDIM + d] + pe;
    }
    __syncthreads();

    for (int l = 0; l < 5; ++l) {
        gemm16<128, 128, 2>(xs, Wqkv + (size_t)(l * 3 + 0) * 16384, bqkv + (l * 3 + 0) * 128, qb, false);
        gemm16<128, 128, 2>(xs, Wqkv + (size_t)(l * 3 + 1) * 16384, bqkv + (l * 3 + 1) * 128, kb, false);
        gemm16<128, 128, 2>(xs, Wqkv + (size_t)(l * 3 + 2) * 16384, bqkv + (l * 3 + 2) * 128, vb, false);
        __syncthreads();
        // scores [h][tq][tk]
        for (int idx = tid; idx < 1024; idx += 256) {
            int hh = idx >> 8, tq = (idx >> 4) & 15, tk = idx & 15;
            const float* qp = qb + tq * 128 + hh * 32;
            const float* kp = kb + tk * 128 + hh * 32;
            float a = 0.f;
#pragma unroll
            for (int d = 0; d < 32; ++d) a += qp[d] * kp[d];
            sc[idx] = a * 0.17677669529663687f;   // 1/sqrt(32)
        }
        __syncthreads();
        if (tid < 64) {   // softmax per (h,tq) row
            int base = tid * 16;
            float mx = -1e30f;
#pragma unroll
            for (int u = 0; u < 16; ++u) mx = fmaxf(mx, sc[base + u]);
            float s = 0.f;
#pragma unroll
            for (int u = 0; u < 16; ++u) { float e = __expf(sc[base + u] - mx); sc[base + u] = e; s += e; }
            float inv = 1.f / s;
#pragma unroll
            for (int u = 0; u < 16; ++u) sc[base + u] *= inv;
        }
        __syncthreads();
        // o = P @ V  -> qb (safe: all qb reads happened before prior barrier)
        {
            int o = tid & 127, r0 = (tid >> 7) * 8, hh = o >> 5;
            float acc[8] = {0, 0, 0, 0, 0, 0, 0, 0};
            for (int u = 0; u < 16; ++u) {
                float vv = vb[u * 128 + o];
#pragma unroll
                for (int r = 0; r < 8; ++r) acc[r] += sc[(hh * 16 + r0 + r) * 16 + u] * vv;
            }
#pragma unroll
            for (int r = 0; r < 8; ++r) qb[(r0 + r) * 128 + o] = acc[r];
        }
        __syncthreads();
        gemm16<128, 128, 2>(qb, Wo + (size_t)l * 16384, bo + l * 128, tb, false);
        __syncthreads();
        addln(xs, tb, ln1s + l * 128, ln1b + l * 128);
        gemm16<128, 512, 4>(xs, Wff1 + (size_t)l * 65536, bff1 + l * 512, hid, true);
        __syncthreads();
        gemm16<512, 128, 2>(hid, Wff2 + (size_t)l * 65536, bff2 + l * 128, tb, false);
        __syncthreads();
        addln(xs, tb, ln2s + l * 128, ln2b + l * 128);
    }
    for (int idx = tid; idx < 2048; idx += 256)
        out[(size_t)m * 2048 + idx] = xs[idx];
}

extern "C" void kernel_launch(void* const* d_in, const int* in_sizes, int n_in,
                              void* d_out, int out_size, void* d_ws, size_t ws_size,
                              hipStream_t stream) {
    (void)in_sizes; (void)n_in; (void)out_size; (void)ws_size;
    const int*   ego  = (const int*)d_in[0];
    const float* pos  = (const float*)d_in[1];
    const float* adj  = (const float*)d_in[2];
    const float* g1W  = (const float*)d_in[3];
    const float* g1as = (const float*)d_in[4];
    const float* g1ad = (const float*)d_in[5];
    const float* g1b  = (const float*)d_in[6];
    const float* gW   = (const float*)d_in[7];
    const float* gas  = (const float*)d_in[8];
    const float* gad  = (const float*)d_in[9];
    const float* gb   = (const float*)d_in[10];
    const float* Wqkv = (const float*)d_in[11];
    const float* bqkv = (const float*)d_in[12];
    const float* Wo   = (const float*)d_in[13];
    const float* bo   = (const float*)d_in[14];
    const float* l1s  = (const float*)d_in[15];
    const float* l1b  = (const float*)d_in[16];
    const float* l2s  = (const float*)d_in[17];
    const float* l2b  = (const float*)d_in[18];
    const float* Wff1 = (const float*)d_in[19];
    const float* bff1 = (const float*)d_in[20];
    const float* Wff2 = (const float*)d_in[21];
    const float* bff2 = (const float*)d_in[22];

    float* ws  = (float*)d_ws;
    float* x0  = ws;                       // 2,097,152 f
    float* x1  = x0 + 2097152;             // 2,097,152 f
    float* hb  = x1 + 2097152;             // 8,388,608 f
    float* ssb = hb + 8388608;             // 65,536 f
    float* sdb = ssb + 65536;              // 65,536 f
    float* mfl = sdb + 65536;              // 16,384 f
    int*   cnt = (int*)(mfl + 16384);      // 16,384 i
    int*   nbr = cnt + 16384;              // 1,048,576 i   (total ~55.2 MB)

    k_init<<<64, 256, 0, stream>>>(ego, mfl, cnt);
    k_edges<<<256, 256, 0, stream>>>(adj, mfl, cnt, nbr);

    // GAT layer 1 (F=2)
    k_gat1_h<<<32768, 256, 0, stream>>>(pos, g1W, hb);
    k_ssd<<<NROWS, 128, 0, stream>>>(hb, g1as, g1ad, ssb, sdb);
    k_agg<<<NROWS, 128, 0, stream>>>(hb, ssb, sdb, cnt, nbr, mfl, g1b, x0);

    float* xin = x0; float* xout = x1;
    for (int L = 0; L < 5; ++L) {
        k_gat_h<<<1024, 256, 0, stream>>>(xin, gW + (size_t)L * 65536, hb);
        k_ssd<<<NROWS, 128, 0, stream>>>(hb, gas + L * 512, gad + L * 512, ssb, sdb);
        k_agg<<<NROWS, 128, 0, stream>>>(hb, ssb, sdb, cnt, nbr, mfl, gb + L * 128, xout);
        float* tmp = xin; xin = xout; xout = tmp;
    }

    k_tf<<<MM, 256, 0, stream>>>(xin, Wqkv, bqkv, Wo, bo, l1s, l1b, l2s, l2b,
                                 Wff1, bff1, Wff2, bff2, (float*)d_out);
}